// Round 11
// baseline (528.749 us; speedup 1.0000x reference)
//
#include <hip/hip_runtime.h>
#include <cmath>

#define HID 128

typedef __attribute__((ext_vector_type(8))) short bf16x8;
typedef __attribute__((ext_vector_type(4))) float f32x4;
typedef __attribute__((ext_vector_type(16))) float f32x16;

__device__ __forceinline__ unsigned short f2bf(float f) {
    union { float f; unsigned int i; } c; c.f = f;
    unsigned int r = c.i + 0x7fffu + ((c.i >> 16) & 1u);
    return (unsigned short)(r >> 16);
}
__device__ __forceinline__ unsigned cvt_pk(float lo, float hi) {
    unsigned r;
    asm("v_cvt_pk_bf16_f32 %0, %1, %2" : "=v"(r) : "v"(lo), "v"(hi));
    return r;
}
__device__ __forceinline__ float bflo(unsigned u) {
    union { unsigned i; float f; } c; c.i = u << 16; return c.f;
}
__device__ __forceinline__ float bfhi(unsigned u) {
    union { unsigned i; float f; } c; c.i = u & 0xffff0000u; return c.f;
}
__device__ __forceinline__ float silu_f(float v) {
    float t = __builtin_amdgcn_exp2f(-1.44269504f * v);
    return v * __builtin_amdgcn_rcpf(1.0f + t);
}
__device__ __forceinline__ float sigmoid_f(float v) {
    return __builtin_amdgcn_rcpf(1.0f + __builtin_amdgcn_exp2f(-1.44269504f * v));
}
typedef __fp16 fp16x2 __attribute__((ext_vector_type(2)));
__device__ __forceinline__ unsigned pkrtz(float lo, float hi) {
    union { fp16x2 h; unsigned u; } cv;
    cv.h = __builtin_amdgcn_cvt_pkrtz(lo, hi);
    return cv.u;
}
__device__ __forceinline__ void atomic_pk_add_f16_raw(void* p, unsigned u) {
    unsigned long long a = (unsigned long long)p;
    asm volatile("global_atomic_pk_add_f16 %0, %1, off" :: "v"(a), "v"(u));
}

// ---------------------------------------------------------------------------
// Weight prep. Edge matrices (We1, We2, Wc1): 32x32 A-fragments of W^T:
//   dst[((t*KC + kc)*64 + lane)*8 + j] = W[k][t*32 + (lane&31)]
//   k = kc*16 + (lane>>5)*4 + (j&3) + 8*(j>>2)
// Node matrices (Wn1, Wn2): 16x16 A-fragments (old mapping):
//   dst[((nt*KC + kc)*64 + lane)*8 + j] = W[k][nt*16 + (lane&15)]
//   k = kc*32 + (lane>>4)*4 + (j&3) + 16*(j>>2)
// ---------------------------------------------------------------------------
__global__ __launch_bounds__(256) void egnn_prep(
    const float* __restrict__ We1, const float* __restrict__ We2,
    const float* __restrict__ Wc1, const float* __restrict__ Wn1,
    const float* __restrict__ Wn2,
    short* __restrict__ We1p, short* __restrict__ We2p, short* __restrict__ Wc1p,
    short* __restrict__ Wn1p, short* __restrict__ Wn2p)
{
    int t = blockIdx.x * 256 + threadIdx.x;
    int frag = t >> 6, lane = t & 63;
    if (frag >= 224) return;
    if (frag < 128) {
        // 32x32 format
        const float* W; short* dst; int KC, f;
        if (frag < 64)      { W = We1; dst = We1p; KC = 16; f = frag; }
        else if (frag < 96) { W = We2; dst = We2p; KC = 8;  f = frag - 64; }
        else                { W = Wc1; dst = Wc1p; KC = 8;  f = frag - 96; }
        int tt = f / KC, kc = f % KC;
        int n = tt * 32 + (lane & 31);
        short* d = dst + (((size_t)tt * KC + kc) * 64 + lane) * 8;
        #pragma unroll
        for (int j = 0; j < 8; ++j) {
            int k = kc * 16 + ((lane >> 5) << 2) + (j & 3) + ((j >> 2) << 3);
            d[j] = (short)f2bf(W[(size_t)k * HID + n]);
        }
    } else {
        // 16x16 format (node kernel)
        const float* W; short* dst; int KC, f;
        if (frag < 192) { W = Wn1; dst = Wn1p; KC = 8; f = frag - 128; }
        else            { W = Wn2; dst = Wn2p; KC = 4; f = frag - 192; }
        int nt = f / KC, kc = f % KC;
        int n = nt * 16 + (lane & 15);
        short* d = dst + (((size_t)nt * KC + kc) * 64 + lane) * 8;
        #pragma unroll
        for (int j = 0; j < 8; ++j) {
            int k = kc * 32 + ((lane >> 4) << 2) + (j & 3) + ((j >> 2) << 4);
            d[j] = (short)f2bf(W[(size_t)k * HID + n]);
        }
    }
}

// ---- h -> bf16 pack ----
__global__ __launch_bounds__(256) void egnn_hpack(
    const float* __restrict__ h, short* __restrict__ h16, int N)
{
    int t = blockIdx.x * 256 + threadIdx.x;
    if (t < N * 32) {
        float4 v = *(const float4*)(h + (size_t)t * 4);
        uint2 p; p.x = cvt_pk(v.x, v.y); p.y = cvt_pk(v.z, v.w);
        *(uint2*)(h16 + (size_t)t * 4) = p;
    }
}

// ---------------------------------------------------------------------------
// Edge kernel: 128 edges/block, 4 waves; wave w owns edges w*32..w*32+31
// via 32x32x16 MFMA (N=32 edges = lane&31, M=128 features = 4 tiles).
// Layers chain fully in-register; scatter via stride-264 LDS relay.
// ---------------------------------------------------------------------------
__global__ __launch_bounds__(256) void egnn_edge_mfma(
    const short* __restrict__ h16, const float* __restrict__ x,
    const int* __restrict__ ei, int E,
    const short* __restrict__ We1p, const float* __restrict__ We1,
    const float* __restrict__ be1,
    const short* __restrict__ We2p, const float* __restrict__ be2,
    const float* __restrict__ Wg, const float* __restrict__ bg,
    const short* __restrict__ Wc1p, const float* __restrict__ bc1,
    const float* __restrict__ Wc2, const float* __restrict__ bc2,
    short* __restrict__ m16, float* __restrict__ coord_aggr)
{
    __shared__ short sRelay[128 * 132];     // 128 rows x 264B (256B data + 8B bank pad)
    __shared__ float s_be1[128], s_w256[128], s_be2[128];
    __shared__ float s_wg[128], s_bc1[128], s_wc2[128];

    const int tid  = threadIdx.x;
    const int lane = tid & 63;
    const int w    = tid >> 6;
    const int el   = lane & 31;         // edge within wave
    const int hl   = lane >> 5;         // k-half group
    const int e0   = blockIdx.x * 128;
    const int ne   = min(128, E - e0);
    const int eloc = w * 32 + el;
    const int eg   = e0 + ((eloc < ne) ? eloc : 0);

    if (tid < 128) {
        s_be1[tid]  = be1[tid];
        s_w256[tid] = We1[(size_t)256 * HID + tid];
        s_be2[tid]  = be2[tid];
        s_wg[tid]   = Wg[tid];
        s_bc1[tid]  = bc1[tid];
        s_wc2[tid]  = Wc2[tid];
    }

    const int nr = ei[eg];
    const int nc = ei[E + eg];
    float dx = x[nc * 3 + 0] - x[nr * 3 + 0];
    float dy = x[nc * 3 + 1] - x[nr * 3 + 1];
    float dz = x[nc * 3 + 2] - x[nr * 3 + 2];
    float dist = sqrtf(dx * dx + dy * dy + dz * dz);

    // ---- gather 16 B-fragments (kc 0-7: h[col], 8-15: h[row]); issued early
    bf16x8 b[16];
    {
        const short* pc = h16 + (size_t)nc * HID + hl * 4;
        const short* pr = h16 + (size_t)nr * HID + hl * 4;
        #pragma unroll
        for (int kc = 0; kc < 8; ++kc) {
            ((uint2*)&b[kc])[0] = *(const uint2*)(pc + kc * 16);
            ((uint2*)&b[kc])[1] = *(const uint2*)(pc + kc * 16 + 8);
        }
        #pragma unroll
        for (int kc = 0; kc < 8; ++kc) {
            ((uint2*)&b[8 + kc])[0] = *(const uint2*)(pr + kc * 16);
            ((uint2*)&b[8 + kc])[1] = *(const uint2*)(pr + kc * 16 + 8);
        }
    }
    __syncthreads();    // consts ready

    const bf16x8* A1 = (const bf16x8*)We1p;
    const bf16x8* A2 = (const bf16x8*)We2p;
    const bf16x8* A3 = (const bf16x8*)Wc1p;

    // ---- L1: K=256, 4 M-tiles, dist column folded into init
    f32x16 acc[4];
    #pragma unroll
    for (int t = 0; t < 4; ++t)
        #pragma unroll
        for (int q = 0; q < 4; ++q) {
            float4 bb = *(const float4*)&s_be1[32 * t + 4 * hl + 8 * q];
            float4 ww = *(const float4*)&s_w256[32 * t + 4 * hl + 8 * q];
            acc[t][4 * q + 0] = bb.x + dist * ww.x;
            acc[t][4 * q + 1] = bb.y + dist * ww.y;
            acc[t][4 * q + 2] = bb.z + dist * ww.z;
            acc[t][4 * q + 3] = bb.w + dist * ww.w;
        }
    #pragma unroll
    for (int kc = 0; kc < 16; ++kc)
        #pragma unroll
        for (int t = 0; t < 4; ++t)
            acc[t] = __builtin_amdgcn_mfma_f32_32x32x16_bf16(
                A1[((size_t)t * 16 + kc) * 64 + lane], b[kc], acc[t], 0, 0, 0);

    // ---- silu + pack -> Bn[8] (L2 B-fragments, pure register remap)
    bf16x8 Bn[8];
    #pragma unroll
    for (int kc2 = 0; kc2 < 8; ++kc2) {
        int t = kc2 >> 1, base = (kc2 & 1) * 8;
        unsigned* d = (unsigned*)&Bn[kc2];
        #pragma unroll
        for (int j2 = 0; j2 < 4; ++j2)
            d[j2] = cvt_pk(silu_f(acc[t][base + 2 * j2]),
                           silu_f(acc[t][base + 2 * j2 + 1]));
    }

    // ---- L2: K=128
    #pragma unroll
    for (int t = 0; t < 4; ++t)
        #pragma unroll
        for (int q = 0; q < 4; ++q) {
            float4 bb = *(const float4*)&s_be2[32 * t + 4 * hl + 8 * q];
            acc[t][4 * q + 0] = bb.x; acc[t][4 * q + 1] = bb.y;
            acc[t][4 * q + 2] = bb.z; acc[t][4 * q + 3] = bb.w;
        }
    #pragma unroll
    for (int kc2 = 0; kc2 < 8; ++kc2)
        #pragma unroll
        for (int t = 0; t < 4; ++t)
            acc[t] = __builtin_amdgcn_mfma_f32_32x32x16_bf16(
                A2[((size_t)t * 8 + kc2) * 64 + lane], Bn[kc2], acc[t], 0, 0, 0);

    // ---- silu (in place) + gate partial dot
    float gp = 0.f;
    #pragma unroll
    for (int t = 0; t < 4; ++t)
        #pragma unroll
        for (int q = 0; q < 4; ++q) {
            float4 wg4 = *(const float4*)&s_wg[32 * t + 4 * hl + 8 * q];
            float s0 = silu_f(acc[t][4 * q + 0]);
            float s1 = silu_f(acc[t][4 * q + 1]);
            float s2 = silu_f(acc[t][4 * q + 2]);
            float s3 = silu_f(acc[t][4 * q + 3]);
            acc[t][4 * q + 0] = s0; acc[t][4 * q + 1] = s1;
            acc[t][4 * q + 2] = s2; acc[t][4 * q + 3] = s3;
            gp += s0 * wg4.x + s1 * wg4.y + s2 * wg4.z + s3 * wg4.w;
        }
    gp += __shfl_xor(gp, 32, 64);
    float gate = sigmoid_f(gp + bg[0]);
    gate *= (eloc < ne) ? 1.0f : 0.0f;      // zero pad-slot payloads

    // ---- gated pack: B3[8] (bf16, L3 B-frags) + f16 words -> relay row
    char* relayRow = (char*)sRelay + (size_t)eloc * 264;
    bf16x8 B3[8];
    #pragma unroll
    for (int kc2 = 0; kc2 < 8; ++kc2) {
        int t = kc2 >> 1, base = (kc2 & 1) * 8;
        unsigned* d = (unsigned*)&B3[kc2];
        uint2 w0, w1;
        {
            float l0 = silu_f(0.f); // dummy to keep structure simple (unused)
            (void)l0;
        }
        {
            float lo = acc[t][base + 0] * gate, hi = acc[t][base + 1] * gate;
            d[0] = cvt_pk(lo, hi); w0.x = pkrtz(lo, hi);
        }
        {
            float lo = acc[t][base + 2] * gate, hi = acc[t][base + 3] * gate;
            d[1] = cvt_pk(lo, hi); w0.y = pkrtz(lo, hi);
        }
        {
            float lo = acc[t][base + 4] * gate, hi = acc[t][base + 5] * gate;
            d[2] = cvt_pk(lo, hi); w1.x = pkrtz(lo, hi);
        }
        {
            float lo = acc[t][base + 6] * gate, hi = acc[t][base + 7] * gate;
            d[3] = cvt_pk(lo, hi); w1.y = pkrtz(lo, hi);
        }
        // features 16*kc2+4*hl+{0..3} at byte 32*kc2+8*hl ; +{8..11} at +16
        *(uint2*)(relayRow + 32 * kc2 + 8 * hl)      = w0;
        *(uint2*)(relayRow + 32 * kc2 + 8 * hl + 16) = w1;
    }

    // ---- dense m scatter: wave iterates its 32 edges; batched 8-ahead LDS
    // reads; one pk-f16 atomic per (edge, lane) -> 4 full lines/edge.
    // Relay rows [w*32, w*32+32) are wave-private: no barrier needed.
    #pragma unroll
    for (int i0 = 0; i0 < 32; i0 += 8) {
        unsigned vv[8]; int cc[8];
        #pragma unroll
        for (int i = 0; i < 8; ++i) {
            int e = w * 32 + i0 + i;
            cc[i] = __shfl(nc, i0 + i, 64);
            vv[i] = *(const unsigned*)((const char*)sRelay + (size_t)e * 264 + lane * 4);
        }
        #pragma unroll
        for (int i = 0; i < 8; ++i) {
            if (e0 + w * 32 + i0 + i < E)
                atomic_pk_add_f16_raw(m16 + (size_t)cc[i] * HID + lane * 2, vv[i]);
        }
    }

    // ---- L3: K=128, tile-serial (transient 16-reg acc), coord-weight dot
    float cwp = 0.f;
    #pragma unroll
    for (int t = 0; t < 4; ++t) {
        f32x16 a3;
        #pragma unroll
        for (int q = 0; q < 4; ++q) {
            float4 bb = *(const float4*)&s_bc1[32 * t + 4 * hl + 8 * q];
            a3[4 * q + 0] = bb.x; a3[4 * q + 1] = bb.y;
            a3[4 * q + 2] = bb.z; a3[4 * q + 3] = bb.w;
        }
        #pragma unroll
        for (int kc2 = 0; kc2 < 8; ++kc2)
            a3 = __builtin_amdgcn_mfma_f32_32x32x16_bf16(
                A3[((size_t)t * 8 + kc2) * 64 + lane], B3[kc2], a3, 0, 0, 0);
        #pragma unroll
        for (int q = 0; q < 4; ++q) {
            float4 wc4 = *(const float4*)&s_wc2[32 * t + 4 * hl + 8 * q];
            cwp += silu_f(a3[4 * q + 0]) * wc4.x + silu_f(a3[4 * q + 1]) * wc4.y
                 + silu_f(a3[4 * q + 2]) * wc4.z + silu_f(a3[4 * q + 3]) * wc4.w;
        }
    }
    cwp += __shfl_xor(cwp, 32, 64);
    float cw = cwp + bc2[0];
    if (hl == 0 && eloc < ne) {
        atomicAdd(&coord_aggr[nc * 3 + 0], dx * cw);
        atomicAdd(&coord_aggr[nc * 3 + 1], dy * cw);
        atomicAdd(&coord_aggr[nc * 3 + 2], dz * cw);
    }
}

// ---------------------------------------------------------------------------
// Node kernel: 16x16 transposed structure, 64 nodes/block (unchanged).
// ---------------------------------------------------------------------------
__global__ __launch_bounds__(256) void egnn_node_mfma(
    const float* __restrict__ h, const short* __restrict__ h16,
    const float* __restrict__ x,
    const short* __restrict__ m16, const float* __restrict__ coord_aggr,
    const short* __restrict__ Wn1p, const float* __restrict__ bn1,
    const short* __restrict__ Wn2p, const float* __restrict__ bn2,
    float* __restrict__ h_out, float* __restrict__ x_out, int N)
{
    __shared__ short sStage[64 * 256];
    __shared__ float s_bn1[128], s_bn2[128];

    const int tid  = threadIdx.x;
    const int lane = tid & 63;
    const int w    = tid >> 6;
    const int l15  = lane & 15;
    const int g    = lane >> 4;
    const int n0   = blockIdx.x * 64;

    if (tid < 128) { s_bn1[tid] = bn1[tid]; s_bn2[tid] = bn2[tid]; }

    if (tid < 192) {
        int gi = n0 * 3 + tid;
        if (gi < 3 * N) x_out[gi] = x[gi] + coord_aggr[gi];
    }

    #pragma unroll
    for (int it = 0; it < 16; ++it) {
        int e = w + 4 * it;
        int q = lane;
        int node = min(n0 + e, N - 1);
        uint2 pk;
        if (q < 32) {
            pk = *(const uint2*)(h16 + (size_t)node * HID + (size_t)q * 4);
        } else {
            uint2 hv = *(const uint2*)((const char*)m16 + (size_t)node * 256 + (size_t)(q & 31) * 8);
            const __fp16* hp = (const __fp16*)&hv;
            pk.x = cvt_pk((float)hp[0], (float)hp[1]);
            pk.y = cvt_pk((float)hp[2], (float)hp[3]);
        }
        *(uint2*)((char*)sStage + e * 512 + ((q * 8) ^ ((e & 7) << 4))) = pk;
    }
    __syncthreads();

    const int nloc = w * 16 + l15;
    const int node = n0 + nloc;
    const char* stageRow = (const char*)sStage + nloc * 512;
    const int sw = (nloc & 7) << 4;
    const bf16x8* A1 = (const bf16x8*)Wn1p;
    const bf16x8* A2 = (const bf16x8*)Wn2p;

    f32x4 acc[8];
    #pragma unroll
    for (int mt = 0; mt < 8; ++mt) {
        int f = mt * 16 + g * 4;
        #pragma unroll
        for (int r = 0; r < 4; ++r) acc[mt][r] = s_bn1[f + r];
    }
    #pragma unroll
    for (int kc = 0; kc < 8; ++kc) {
        int kb = kc * 64 + g * 8;
        uint2 lo = *(const uint2*)(stageRow + ((kb     ) ^ sw));
        uint2 hi = *(const uint2*)(stageRow + ((kb + 32) ^ sw));
        bf16x8 b; ((uint2*)&b)[0] = lo; ((uint2*)&b)[1] = hi;
        #pragma unroll
        for (int mt = 0; mt < 8; ++mt)
            acc[mt] = __builtin_amdgcn_mfma_f32_16x16x32_bf16(A1[(mt * 8 + kc) * 64 + lane], b, acc[mt], 0, 0, 0);
    }

    bf16x8 Bn[4];
    #pragma unroll
    for (int kc = 0; kc < 4; ++kc) {
        unsigned* d = (unsigned*)&Bn[kc];
        d[0] = cvt_pk(silu_f(acc[2 * kc][0]),     silu_f(acc[2 * kc][1]));
        d[1] = cvt_pk(silu_f(acc[2 * kc][2]),     silu_f(acc[2 * kc][3]));
        d[2] = cvt_pk(silu_f(acc[2 * kc + 1][0]), silu_f(acc[2 * kc + 1][1]));
        d[3] = cvt_pk(silu_f(acc[2 * kc + 1][2]), silu_f(acc[2 * kc + 1][3]));
    }

    f32x4 acc2[8];
    #pragma unroll
    for (int mt = 0; mt < 8; ++mt) {
        int f = mt * 16 + g * 4;
        #pragma unroll
        for (int r = 0; r < 4; ++r) acc2[mt][r] = s_bn2[f + r];
    }
    #pragma unroll
    for (int kc = 0; kc < 4; ++kc)
        #pragma unroll
        for (int mt = 0; mt < 8; ++mt)
            acc2[mt] = __builtin_amdgcn_mfma_f32_16x16x32_bf16(A2[(mt * 4 + kc) * 64 + lane], Bn[kc], acc2[mt], 0, 0, 0);

    if (node < N) {
        #pragma unroll
        for (int mt = 0; mt < 8; ++mt) {
            size_t base = (size_t)node * HID + mt * 16 + g * 4;
            float4 hres = *(const float4*)&h[base];
            float4 o;
            o.x = acc2[mt][0] + hres.x;
            o.y = acc2[mt][1] + hres.y;
            o.z = acc2[mt][2] + hres.z;
            o.w = acc2[mt][3] + hres.w;
            *(float4*)&h_out[base] = o;
        }
    }
}

extern "C" void kernel_launch(void* const* d_in, const int* in_sizes, int n_in,
                              void* d_out, int out_size, void* d_ws, size_t ws_size,
                              hipStream_t stream) {
    const float* h   = (const float*)d_in[0];
    const float* x   = (const float*)d_in[1];
    const int*   ei  = (const int*)d_in[2];
    const float* We1 = (const float*)d_in[3];
    const float* be1 = (const float*)d_in[4];
    const float* We2 = (const float*)d_in[5];
    const float* be2 = (const float*)d_in[6];
    const float* Wg  = (const float*)d_in[7];
    const float* bg  = (const float*)d_in[8];
    const float* Wn1 = (const float*)d_in[9];
    const float* bn1 = (const float*)d_in[10];
    const float* Wn2 = (const float*)d_in[11];
    const float* bn2 = (const float*)d_in[12];
    const float* Wc1 = (const float*)d_in[13];
    const float* bc1 = (const float*)d_in[14];
    const float* Wc2 = (const float*)d_in[15];
    const float* bc2 = (const float*)d_in[16];

    const int N = in_sizes[0] / HID;
    const int E = in_sizes[2] / 2;

    // workspace layout
    char* p = (char*)d_ws;
    short* m16        = (short*)p;  p += (size_t)N * 256;   // N*128 f16
    float* coord_aggr = (float*)p;  p += (size_t)N * 12;    // N*3 f32
    // ---- memset covers [d_ws, p) = N*268 bytes ----
    short* h16        = (short*)p;  p += (size_t)N * 256;   // N*128 bf16
    short* We1p       = (short*)p;  p += 256 * 128 * 2;
    short* We2p       = (short*)p;  p += 128 * 128 * 2;
    short* Wc1p       = (short*)p;  p += 128 * 128 * 2;
    short* Wn1p       = (short*)p;  p += 256 * 128 * 2;
    short* Wn2p       = (short*)p;  p += 128 * 128 * 2;

    (void)hipMemsetAsync(d_ws, 0, (size_t)N * 268, stream);

    float* h_out = (float*)d_out;
    float* x_out = h_out + (size_t)N * HID;

    egnn_prep<<<dim3(56), dim3(256), 0, stream>>>(
        We1, We2, Wc1, Wn1, Wn2, We1p, We2p, Wc1p, Wn1p, Wn2p);
    egnn_hpack<<<dim3((N * 32 + 255) / 256), dim3(256), 0, stream>>>(h, h16, N);
    egnn_edge_mfma<<<dim3((E + 127) / 128), dim3(256), 0, stream>>>(
        h16, x, ei, E, We1p, We1, be1, We2p, be2, Wg, bg, Wc1p, bc1, Wc2, bc2,
        m16, coord_aggr);
    egnn_node_mfma<<<dim3((N + 63) / 64), dim3(256), 0, stream>>>(
        h, h16, x, m16, coord_aggr, Wn1p, bn1, Wn2p, bn2, h_out, x_out, N);
}